// Round 9
// baseline (415.168 us; speedup 1.0000x reference)
//
#include <hip/hip_runtime.h>

// out[b,m,f,t] = sum_c W[m,f,c] * x[b,m,c,t]
// x: [B=256][NM=5][NC=64][T=1024] f32, W: [NM=5][NF=40][NC=64] f32
// out: [B][NM][NF=40][T] f32
//
// R8: canonical LDS staging. Two invariants no prior round satisfied at once:
//  (1) per-thread reg demand (~35) < 64  -> spill-free under ANY allocator
//      policy (R2/R4/R6 trap defused structurally, no attributes needed);
//  (2) each x element enters the CU once, shared via LDS (R7's L1-thrash
//      from 4 waves re-reading global is gone; LDS is 160 KB, no thrash).
// Block = 256T, tile (bm, 128 t): stage tile[64][128] (32 KB) coalesced,
// barrier, wave-pairs split f (20 f/thread). LDS pins 5 blocks/CU ->
// 1280 resident, grid 10240 = exactly 8 generations, zero dispatch tail.

#define B_  256
#define NM_ 5
#define NC_ 64
#define T_  1024
#define NF_ 40
#define TT_ 128
#define FG_ 20        // f's per f-group (2 groups of waves)

typedef float v4f __attribute__((ext_vector_type(4)));

__global__ __launch_bounds__(256) void trca_einsum_kernel(
    const float* __restrict__ x,
    const float* __restrict__ W,
    float* __restrict__ out)
{
    __shared__ float tile[NC_][TT_];   // 32 KB -> 5 blocks/CU

    const int tid   = threadIdx.x;
    const int ttile = blockIdx.x & 7;
    const int bm    = blockIdx.x >> 3;      // b*NM + m
    const int m     = bm % NM_;
    const int t0    = ttile * TT_;

    const float* __restrict__ xbase = x + (size_t)bm * NC_ * T_ + t0;

    // ---- Stage x tile: 8 float4/thread, fully coalesced (1 KB/wave-instr),
    //      linear LDS, contiguous b128 writes (conflict-free). ----
#pragma unroll
    for (int i = 0; i < 8; ++i) {
        const int j   = tid + 256 * i;      // float4 index 0..2047
        const int row = j >> 5;             // 32 float4 per 128-float row
        const int c4  = j & 31;
        const v4f v = *reinterpret_cast<const v4f*>(xbase + (size_t)row * T_ + c4 * 4);
        *reinterpret_cast<v4f*>(&tile[row][c4 * 4]) = v;
    }
    __syncthreads();

    // ---- Compute: thread = (t, f-group). Wave-uniform f base. ----
    const int l = tid & 63;
    const int h = (tid >> 6) & 1;
    const int g = tid >> 7;                 // 0..1
    const int t = h * 64 + l;

    const float* __restrict__ wp = W + (size_t)m * NF_ * NC_ + (size_t)g * FG_ * NC_;
    float* __restrict__ op = out + (size_t)bm * NF_ * T_ + (size_t)g * FG_ * T_ + t0 + t;

    float acc[FG_];
#pragma unroll
    for (int f = 0; f < FG_; ++f) acc[f] = 0.0f;

#pragma unroll 1
    for (int cc = 0; cc < NC_; cc += 4) {
        float xv[4];
#pragma unroll
        for (int i = 0; i < 4; ++i) xv[i] = tile[cc + i][t];   // 2-way bank alias = free
#pragma unroll
        for (int i = 0; i < 4; ++i) {
#pragma unroll
            for (int f = 0; f < FG_; ++f) {
                acc[f] += wp[f * NC_ + cc + i] * xv[i];        // w: wave-uniform s_load
            }
        }
    }

#pragma unroll
    for (int f = 0; f < FG_; ++f) {
        __builtin_nontemporal_store(acc[f], op + (size_t)f * T_);
    }
}

extern "C" void kernel_launch(void* const* d_in, const int* in_sizes, int n_in,
                              void* d_out, int out_size, void* d_ws, size_t ws_size,
                              hipStream_t stream)
{
    const float* x = (const float*)d_in[0];
    const float* W = (const float*)d_in[1];
    float* out = (float*)d_out;

    const int grid = B_ * NM_ * (T_ / TT_);   // 10240 blocks = 8 exact generations
    trca_einsum_kernel<<<grid, 256, 0, stream>>>(x, W, out);
}

// Round 10
// 124.833 us; speedup vs baseline: 3.3258x; 3.3258x over previous
//
#include <hip/hip_runtime.h>

// out[b,m,f,t] = sum_c W[m,f,c] * x[b,m,c,t]
// x: [B=256][NM=5][NC=64][T=1024] f32, W: [NM=5][NF=40][NC=64] f32
// out: [B][NM][NF=40][T] f32
//
// R9 = R1 (best, 120.9 us) + W s_load batching.
//  - KEEP: grid 2560 (bm x t-half), 256 thr, 2 t/thread (float2),
//    40 f/thread (acc demand ~108 -> honest 4-waves allocation; the
//    40-70-reg zone triggers AGPR demotion, the tid-derived-W variants
//    trigger per-lane vector loads -- both proven fatal in R2-R8).
//  - CHANGE: CCHUNK=8 + f-outer/c-inner FMA order so each f's 8
//    consecutive W dwords (32 B aligned) merge into one s_load_dwordx8:
//    half the scalar-cache round-trips, 16 FMAs amortizing each wait,
//    8 x-loads (4 KB/wave) issued up front for deeper vmcnt pipeline.
//  - CHANGE: plain float2 stores (the 120.9 run used them; nt measured
//    slightly worse in R3).

#define B_  256
#define NM_ 5
#define NC_ 64
#define T_  1024
#define NF_ 40
#define CCHUNK 8

__global__ __launch_bounds__(256, 4) void trca_einsum_kernel(
    const float* __restrict__ x,
    const float* __restrict__ W,
    float* __restrict__ out)
{
    // grid.x = B*NM*2 ; low bit = t-half
    const int tile = blockIdx.x & 1;
    const int bm   = blockIdx.x >> 1;          // b*NM + m
    const int m    = bm % NM_;                 // block-uniform (scalar-safe)
    const int t0   = tile * (T_ / 2) + threadIdx.x * 2;

    const float* __restrict__ xp = x + (size_t)bm * NC_ * T_ + t0;   // stride T_ per c
    const float* __restrict__ wp = W + (size_t)m * NF_ * NC_;        // W[m,f,c]
    float* __restrict__ op = out + (size_t)bm * NF_ * T_ + t0;       // stride T_ per f

    float acc0[NF_], acc1[NF_];
#pragma unroll
    for (int f = 0; f < NF_; ++f) { acc0[f] = 0.0f; acc1[f] = 0.0f; }

#pragma unroll 1
    for (int cc = 0; cc < NC_; cc += CCHUNK) {
        // 8 independent float2 loads up front (4 KB per wave in flight).
        float2 xv[CCHUNK];
#pragma unroll
        for (int i = 0; i < CCHUNK; ++i)
            xv[i] = *reinterpret_cast<const float2*>(xp + (size_t)(cc + i) * T_);

        // f-outer, c-inner: the 8 consecutive wp dwords per f merge into
        // one s_load_dwordx8; 16 FMAs per scalar load. Same per-f c-order
        // as R1 -> bit-identical accumulation.
#pragma unroll
        for (int f = 0; f < NF_; ++f) {
#pragma unroll
            for (int i = 0; i < CCHUNK; ++i) {
                const float w = wp[f * NC_ + cc + i];
                acc0[f] += w * xv[i].x;
                acc1[f] += w * xv[i].y;
            }
        }
    }

#pragma unroll
    for (int f = 0; f < NF_; ++f) {
        *reinterpret_cast<float2*>(op + (size_t)f * T_) = make_float2(acc0[f], acc1[f]);
    }
}

extern "C" void kernel_launch(void* const* d_in, const int* in_sizes, int n_in,
                              void* d_out, int out_size, void* d_ws, size_t ws_size,
                              hipStream_t stream)
{
    const float* x = (const float*)d_in[0];
    const float* W = (const float*)d_in[1];
    float* out = (float*)d_out;

    const int grid = B_ * NM_ * 2;   // 2560 blocks
    trca_einsum_kernel<<<grid, 256, 0, stream>>>(x, W, out);
}